// Round 4
// baseline (26791.913 us; speedup 1.0000x reference)
//
#include <hip/hip_runtime.h>
#include <hip/hip_bf16.h>
#include <math.h>

#define N_TOTAL   32768
#define K_ENT     4096
#define DIM       64
#define BM        64
#define BK        128

// ws layout (float offsets)
#define WS_CBN    0         // 4096 floats: 0.5*||w_k||^2
#define WS_IDX    4096      // 32768 ints: argmax indices
// out layout (fp32 element offsets)
#define OUT_ZQ    0
#define OUT_IDX   2097152
#define OUT_LOSS  2129920
#define OUT_ENC   2134016   // encodings_sum accumulated here directly
#define OUT_EMB   2138112   // embed_sum accumulated here directly

#define NEG_BIG   -3.0e38f   // finite sentinel: safe under fast-math

__device__ __forceinline__ bool better(float a, int ia, float b, int ib) {
  return (a > b) || (a == b && ia < ib);
}

__global__ __launch_bounds__(256) void cbnorm_half_kernel(
    const float* __restrict__ w, float* __restrict__ cbn) {
  int k = blockIdx.x * 256 + threadIdx.x;           // 0..4095
  const float4* p = (const float4*)(w + (size_t)k * DIM);
  float s = 0.f;
  #pragma unroll
  for (int i = 0; i < 16; ++i) {
    float4 v = p[i];
    s = fmaf(v.x, v.x, s); s = fmaf(v.y, v.y, s);
    s = fmaf(v.z, v.z, s); s = fmaf(v.w, v.w, s);
  }
  cbn[k] = 0.5f * s;
}

// BM=64 rows x all K entries per block; BK=128 entry chunks staged in LDS.
// zT/wT stored transposed [d][col] with col ^= ((d>>2)&7)<<2 swizzle so the
// ds_read_b128 compute reads are conflict-free.
__global__ __launch_bounds__(256) void argmax_kernel(
    const float* __restrict__ z, const float* __restrict__ w,
    const float* __restrict__ cbn, int* __restrict__ idx_out,
    float* __restrict__ out_idx) {
  __shared__ float zT[DIM][BM];    // 16 KB — stays intact through the tail
  __shared__ float wT[DIM][BK];    // 32 KB — reused as candidate buffer in tail
  const int tid = threadIdx.x;
  const int n0  = blockIdx.x * BM;
  const int eg  = tid & 31;        // entry group: entries e0 = eg*4
  const int rg  = tid >> 5;        // row group:   rows    r0 = rg*8

  // ---- stage zT (transposed + swizzled), coalesced global reads ----
  #pragma unroll
  for (int i = 0; i < 4; ++i) {
    int li = i * 256 + tid;            // 0..1023
    int r = li >> 4, dq = li & 15;
    float4 v = *(const float4*)(z + (size_t)(n0 + r) * DIM + dq * 4);
    int c = r ^ ((dq & 7) << 2);
    zT[dq*4+0][c] = v.x; zT[dq*4+1][c] = v.y;
    zT[dq*4+2][c] = v.z; zT[dq*4+3][c] = v.w;
  }

  int roffA[8], roffB[8], eoff[8];
  #pragma unroll
  for (int t = 0; t < 8; ++t) {
    int s = t << 2;
    roffA[t] = (rg * 8) ^ s;
    roffB[t] = ((rg * 8) ^ s) ^ 4;
    eoff[t]  = (eg * 4) ^ s;
  }

  float v1[8], v2[8];
  int   i1[8], i2[8];
  #pragma unroll
  for (int i = 0; i < 8; ++i) {
    v1[i] = NEG_BIG; v2[i] = NEG_BIG;
    i1[i] = 0x7fffffff; i2[i] = 0x7fffffff;
  }

  // prefetch weight chunk 0 into registers
  float4 wpre[8];
  #pragma unroll
  for (int i = 0; i < 8; ++i) {
    int li = i * 256 + tid;            // 0..2047
    int e = li >> 4, dq = li & 15;
    wpre[i] = *(const float4*)(w + (size_t)e * DIM + dq * 4);
  }

  for (int kc = 0; kc < K_ENT; kc += BK) {
    __syncthreads();                   // prev compute done (and zT staged)
    #pragma unroll
    for (int i = 0; i < 8; ++i) {
      int li = i * 256 + tid;
      int e = li >> 4, dq = li & 15;
      int c = e ^ ((dq & 7) << 2);
      wT[dq*4+0][c] = wpre[i].x; wT[dq*4+1][c] = wpre[i].y;
      wT[dq*4+2][c] = wpre[i].z; wT[dq*4+3][c] = wpre[i].w;
    }
    __syncthreads();                   // wT ready
    if (kc + BK < K_ENT) {             // prefetch next chunk during compute
      #pragma unroll
      for (int i = 0; i < 8; ++i) {
        int li = i * 256 + tid;
        int e = li >> 4, dq = li & 15;
        wpre[i] = *(const float4*)(w + (size_t)(kc + BK + e) * DIM + dq * 4);
      }
    }

    float acc[8][4];
    #pragma unroll
    for (int i = 0; i < 8; ++i)
      #pragma unroll
      for (int j = 0; j < 4; ++j) acc[i][j] = 0.f;

    #pragma unroll
    for (int d = 0; d < DIM; ++d) {
      const int t = (d >> 2) & 7;
      float4 za = *(const float4*)&zT[d][roffA[t]];
      float4 zb = *(const float4*)&zT[d][roffB[t]];
      float4 wv = *(const float4*)&wT[d][eoff[t]];
      float zz[8] = {za.x, za.y, za.z, za.w, zb.x, zb.y, zb.z, zb.w};
      float ww[4] = {wv.x, wv.y, wv.z, wv.w};
      #pragma unroll
      for (int i = 0; i < 8; ++i)
        #pragma unroll
        for (int j = 0; j < 4; ++j)
          acc[i][j] = fmaf(zz[i], ww[j], acc[i][j]);
    }

    // running top-2 update: score = dot - 0.5*||w||^2 (monotone in sim)
    float4 cn4 = *(const float4*)&cbn[kc + eg * 4];
    float cns[4] = {cn4.x, cn4.y, cn4.z, cn4.w};
    #pragma unroll
    for (int j = 0; j < 4; ++j) {
      int e = kc + eg * 4 + j;
      #pragma unroll
      for (int i = 0; i < 8; ++i) {
        float s = acc[i][j] - cns[j];
        if (better(s, e, v1[i], i1[i])) {
          v2[i] = v1[i]; i2[i] = i1[i];
          v1[i] = s;     i1[i] = e;
        } else if (better(s, e, v2[i], i2[i])) {
          v2[i] = s; i2[i] = e;
        }
      }
    }
  }

  // ---- tail: dump per-lane top-2 to LDS (aliased over wT), serial merge ----
  __syncthreads();                     // all compute done; wT is dead
  float* cv = &wT[0][0];               // 64 rows x 64 slots, 16 KB
  int*   ci = (int*)(cv + 64 * 64);    // 64 rows x 64 slots, 16 KB
  #pragma unroll
  for (int i = 0; i < 8; ++i) {
    int r = rg * 8 + i;
    cv[r * 64 + eg]      = v1[i];
    ci[r * 64 + eg]      = i1[i];
    cv[r * 64 + 32 + eg] = v2[i];
    ci[r * 64 + 32 + eg] = i2[i];
  }
  __syncthreads();

  if (tid < BM) {
    const int r = tid;
    float b1 = NEG_BIG, b2 = NEG_BIG;
    int   j1 = 0x7fffffff, j2 = 0x7fffffff;
    for (int s = 0; s < 64; ++s) {
      float v = cv[r * 64 + s];
      int   j = ci[r * 64 + s];
      if (better(v, j, b1, j1)) { b2 = b1; j2 = j1; b1 = v; j1 = j; }
      else if (better(v, j, b2, j2)) { b2 = v; j2 = j; }
    }
    // fp64 rescore of the two finalists: sd = 2*dot(z,w) - ||w||^2
    double best = -1.0e300;
    int win = (j1 >= 0 && j1 < K_ENT) ? j1 : 0;
    for (int t = 0; t < 2; ++t) {
      int c = t ? j2 : j1;
      if (c < 0 || c >= K_ENT) continue;
      double td = 0.0, ud = 0.0;
      for (int d = 0; d < DIM; ++d) {
        double zv = (double)zT[d][r ^ (((d >> 2) & 7) << 2)];
        double wv = (double)w[(size_t)c * DIM + d];
        td = fma(zv, wv, td);
        ud = fma(wv, wv, ud);
      }
      double sd = 2.0 * td - ud;
      if (sd > best || (sd == best && c < win)) { best = sd; win = c; }
    }
    int n = n0 + r;
    idx_out[n] = win;
    out_idx[n] = (float)win;
  }
}

// one block per (b,s): 8 heads x 64 dims = 512 threads
__global__ __launch_bounds__(512) void gather_kernel(
    const float* __restrict__ z, const float* __restrict__ w,
    const int* __restrict__ idx, float* __restrict__ out_zq,
    float* __restrict__ out_loss, float* __restrict__ enc,
    float* __restrict__ emb) {
  int bs = blockIdx.x;
  int tid = threadIdx.x;
  int h = tid >> 6, d = tid & 63;
  int n = bs * 8 + h;
  int k = idx[n];
  k = (k < 0) ? 0 : ((k > K_ENT - 1) ? (K_ENT - 1) : k);  // safety clamp
  float zv = z[(size_t)n * DIM + d];
  float wv = w[(size_t)k * DIM + d];
  float st = zv + (wv - zv);               // straight-through, ref fp order
  out_zq[(size_t)n * DIM + d] = st;
  float diff = zv - wv;
  float s = diff * diff;
  #pragma unroll
  for (int m = 32; m >= 1; m >>= 1) s += __shfl_down(s, m, 64);
  __shared__ float red[8];
  if ((tid & 63) == 0) red[tid >> 6] = s;
  __syncthreads();
  if (tid == 0) {
    float t = 0.f;
    #pragma unroll
    for (int i = 0; i < 8; ++i) t += red[i];
    out_loss[bs] = t * (1.0f / 512.0f);
  }
  atomicAdd(&emb[(size_t)k * DIM + d], zv);
  if (d == 0) atomicAdd(&enc[k], 1.0f);
}

extern "C" void kernel_launch(void* const* d_in, const int* in_sizes, int n_in,
                              void* d_out, int out_size, void* d_ws, size_t ws_size,
                              hipStream_t stream) {
  const float* z = (const float*)d_in[0];
  const float* w = (const float*)d_in[1];
  float* ws  = (float*)d_ws;
  float* cbn = ws + WS_CBN;
  int*   idx = (int*)(ws + WS_IDX);
  float* out = (float*)d_out;

  // zero the scatter accumulator outputs (enc + emb are contiguous, 1 MB)
  hipMemsetAsync(out + OUT_ENC, 0, (size_t)(4096 + 262144) * sizeof(float),
                 stream);

  cbnorm_half_kernel<<<K_ENT / 256, 256, 0, stream>>>(w, cbn);
  argmax_kernel<<<N_TOTAL / BM, 256, 0, stream>>>(z, w, cbn, idx,
                                                  out + OUT_IDX);
  gather_kernel<<<N_TOTAL / 8, 512, 0, stream>>>(z, w, idx, out + OUT_ZQ,
                                                 out + OUT_LOSS,
                                                 out + OUT_ENC, out + OUT_EMB);
}

// Round 6
// 314.761 us; speedup vs baseline: 85.1183x; 85.1183x over previous
//
#include <hip/hip_runtime.h>
#include <math.h>

#define N_TOTAL   32768
#define K_ENT     4096
#define DIM       64
#define BM        64
#define BK        128

// ws layout (float offsets) — total usage: 16 KB
#define WS_CBN    0         // 4096 floats: 0.5*||w_k||^2
// out layout (fp32 element offsets)
#define OUT_ZQ    0
#define OUT_IDX   2097152
#define OUT_LOSS  2129920
#define OUT_ENC   2134016   // encodings_sum accumulated here directly
#define OUT_EMB   2138112   // embed_sum accumulated here directly

#define NEG_BIG   -3.0e38f   // finite sentinel: safe under fast-math

__device__ __forceinline__ bool better(float a, int ia, float b, int ib) {
  return (a > b) || (a == b && ia < ib);
}

__global__ __launch_bounds__(256) void cbnorm_half_kernel(
    const float* __restrict__ w, float* __restrict__ cbn) {
  int k = blockIdx.x * 256 + threadIdx.x;           // 0..4095
  const float4* p = (const float4*)(w + (size_t)k * DIM);
  float s = 0.f;
  #pragma unroll
  for (int i = 0; i < 16; ++i) {
    float4 v = p[i];
    s = fmaf(v.x, v.x, s); s = fmaf(v.y, v.y, s);
    s = fmaf(v.z, v.z, s); s = fmaf(v.w, v.w, s);
  }
  cbn[k] = 0.5f * s;
}

// BM=64 rows x all K entries per block; BK=128 entry chunks staged in LDS.
// zT/wT stored transposed [d][col] with col ^= ((d>>2)&7)<<2 swizzle so the
// ds_read_b128 compute reads are conflict-free. Swizzle offsets computed
// inline (no runtime-indexed arrays -> no scratch, rule #20); dim-loop unroll
// bounded so the load-hoist window can't blow registers. Tail merge uses an
// ALL-FLOAT LDS protocol (indices encoded as floats, exact for k<2^24) —
// no int-through-float-pointer strict-aliasing UB.
__global__ __launch_bounds__(256, 3) void argmax_kernel(
    const float* __restrict__ z, const float* __restrict__ w,
    const float* __restrict__ cbn, float* __restrict__ out_idx) {
  __shared__ float zT[DIM][BM];    // 16 KB — stays intact through the tail
  __shared__ float wT[DIM][BK];    // 32 KB — reused as candidate buffer in tail
  const int tid = threadIdx.x;
  const int n0  = blockIdx.x * BM;
  const int eg  = tid & 31;        // entry group: entries e0 = eg*4
  const int rg  = tid >> 5;        // row group:   rows    r0 = rg*8

  // ---- stage zT (transposed + swizzled), coalesced global reads ----
  #pragma unroll
  for (int i = 0; i < 4; ++i) {
    int li = i * 256 + tid;            // 0..1023
    int r = li >> 4, dq = li & 15;
    float4 v = *(const float4*)(z + (size_t)(n0 + r) * DIM + dq * 4);
    int c = r ^ ((dq & 7) << 2);
    zT[dq*4+0][c] = v.x; zT[dq*4+1][c] = v.y;
    zT[dq*4+2][c] = v.z; zT[dq*4+3][c] = v.w;
  }

  float v1[8], v2[8];
  int   i1[8], i2[8];
  #pragma unroll
  for (int i = 0; i < 8; ++i) {
    v1[i] = NEG_BIG; v2[i] = NEG_BIG;
    i1[i] = 0; i2[i] = 0;            // valid-id sentinels; always displaced
  }

  for (int kc = 0; kc < K_ENT; kc += BK) {
    __syncthreads();                   // prev compute done (and zT staged)
    // stage wT straight from global (w is L2/L3-resident after first sweep)
    #pragma unroll
    for (int i = 0; i < 8; ++i) {
      int li = i * 256 + tid;          // 0..2047
      int e = li >> 4, dq = li & 15;
      float4 v = *(const float4*)(w + (size_t)(kc + e) * DIM + dq * 4);
      int c = e ^ ((dq & 7) << 2);
      wT[dq*4+0][c] = v.x; wT[dq*4+1][c] = v.y;
      wT[dq*4+2][c] = v.z; wT[dq*4+3][c] = v.w;
    }
    __syncthreads();                   // wT ready

    float acc[8][4];
    #pragma unroll
    for (int i = 0; i < 8; ++i)
      #pragma unroll
      for (int j = 0; j < 4; ++j) acc[i][j] = 0.f;

    #pragma unroll 4
    for (int dg = 0; dg < 16; ++dg) {  // 4 dims per group, swizzle const/group
      const int s  = (dg & 7) << 2;
      const int ra = (rg * 8) ^ s;
      const int rb = ra ^ 4;
      const int ec = (eg * 4) ^ s;
      #pragma unroll
      for (int u = 0; u < 4; ++u) {
        const int d = dg * 4 + u;
        float4 za = *(const float4*)&zT[d][ra];
        float4 zb = *(const float4*)&zT[d][rb];
        float4 wv = *(const float4*)&wT[d][ec];
        float zz[8] = {za.x, za.y, za.z, za.w, zb.x, zb.y, zb.z, zb.w};
        float ww[4] = {wv.x, wv.y, wv.z, wv.w};
        #pragma unroll
        for (int i = 0; i < 8; ++i)
          #pragma unroll
          for (int j = 0; j < 4; ++j)
            acc[i][j] = fmaf(zz[i], ww[j], acc[i][j]);
      }
    }

    // running top-2 update: score = dot - 0.5*||w||^2 (monotone in sim)
    float4 cn4 = *(const float4*)&cbn[kc + eg * 4];
    float cns[4] = {cn4.x, cn4.y, cn4.z, cn4.w};
    #pragma unroll
    for (int j = 0; j < 4; ++j) {
      int e = kc + eg * 4 + j;
      #pragma unroll
      for (int i = 0; i < 8; ++i) {
        float s = acc[i][j] - cns[j];
        if (better(s, e, v1[i], i1[i])) {
          v2[i] = v1[i]; i2[i] = i1[i];
          v1[i] = s;     i1[i] = e;
        } else if (better(s, e, v2[i], i2[i])) {
          v2[i] = s; i2[i] = e;
        }
      }
    }
  }

  // ---- tail: dump per-lane top-2 to LDS (aliased over wT, all-float),
  //      then one thread per row merges serially ----
  __syncthreads();                     // all compute done; wT is dead
  float* cv = &wT[0][0];               // scores:  64 rows x 64 slots, 16 KB
  float* cj = cv + 64 * 64;            // indices (as floats), 16 KB
  #pragma unroll
  for (int i = 0; i < 8; ++i) {
    int r = rg * 8 + i;
    cv[r * 64 + eg]      = v1[i];
    cj[r * 64 + eg]      = (float)i1[i];
    cv[r * 64 + 32 + eg] = v2[i];
    cj[r * 64 + 32 + eg] = (float)i2[i];
  }
  __syncthreads();

  if (tid < BM) {
    const int r = tid;
    float b1 = NEG_BIG, b2 = NEG_BIG;
    int   j1 = 0, j2 = 0;
    for (int s = 0; s < 64; ++s) {
      float v = cv[r * 64 + s];
      int   j = (int)cj[r * 64 + s];
      if (better(v, j, b1, j1)) { b2 = b1; j2 = j1; b1 = v; j1 = j; }
      else if (better(v, j, b2, j2)) { b2 = v; j2 = j; }
    }
    // fp64 rescore of the two finalists: sd = 2*dot(z,w) - ||w||^2
    double best = -1.0e300;
    int win = (j1 >= 0 && j1 < K_ENT) ? j1 : 0;
    for (int t = 0; t < 2; ++t) {
      int c = t ? j2 : j1;
      if (c < 0 || c >= K_ENT) continue;
      double td = 0.0, ud = 0.0;
      for (int d = 0; d < DIM; ++d) {
        double zv = (double)zT[d][r ^ (((d >> 2) & 7) << 2)];
        double wv = (double)w[(size_t)c * DIM + d];
        td = fma(zv, wv, td);
        ud = fma(wv, wv, ud);
      }
      double sd = 2.0 * td - ud;
      if (sd > best || (sd == best && c < win)) { best = sd; win = c; }
    }
    out_idx[n0 + r] = (float)win;
  }
}

// one block per (b,s): 8 heads x 64 dims = 512 threads.
// Reads the index back from the fp32 out_idx output (exact small integer).
__global__ __launch_bounds__(512) void gather_kernel(
    const float* __restrict__ z, const float* __restrict__ w,
    const float* __restrict__ idxf, float* __restrict__ out_zq,
    float* __restrict__ out_loss, float* __restrict__ enc,
    float* __restrict__ emb) {
  int bs = blockIdx.x;
  int tid = threadIdx.x;
  int h = tid >> 6, d = tid & 63;
  int n = bs * 8 + h;
  int k = (int)idxf[n];
  k = (k < 0) ? 0 : ((k > K_ENT - 1) ? (K_ENT - 1) : k);  // safety clamp
  float zv = z[(size_t)n * DIM + d];
  float wv = w[(size_t)k * DIM + d];
  float st = zv + (wv - zv);               // straight-through, ref fp order
  out_zq[(size_t)n * DIM + d] = st;
  float diff = zv - wv;
  float s = diff * diff;
  #pragma unroll
  for (int m = 32; m >= 1; m >>= 1) s += __shfl_down(s, m, 64);
  __shared__ float red[8];
  if ((tid & 63) == 0) red[tid >> 6] = s;
  __syncthreads();
  if (tid == 0) {
    float t = 0.f;
    #pragma unroll
    for (int i = 0; i < 8; ++i) t += red[i];
    out_loss[bs] = t * (1.0f / 512.0f);
  }
  atomicAdd(&emb[(size_t)k * DIM + d], zv);
  if (d == 0) atomicAdd(&enc[k], 1.0f);
}

extern "C" void kernel_launch(void* const* d_in, const int* in_sizes, int n_in,
                              void* d_out, int out_size, void* d_ws, size_t ws_size,
                              hipStream_t stream) {
  const float* z = (const float*)d_in[0];
  const float* w = (const float*)d_in[1];
  float* cbn = (float*)d_ws;               // 16 KB of ws
  float* out = (float*)d_out;

  // zero the scatter accumulator outputs (enc + emb are contiguous, 1 MB)
  hipMemsetAsync(out + OUT_ENC, 0, (size_t)(4096 + 262144) * sizeof(float),
                 stream);

  cbnorm_half_kernel<<<K_ENT / 256, 256, 0, stream>>>(w, cbn);
  argmax_kernel<<<N_TOTAL / BM, 256, 0, stream>>>(z, w, cbn, out + OUT_IDX);
  gather_kernel<<<N_TOTAL / 8, 512, 0, stream>>>(z, w, out + OUT_IDX,
                                                 out + OUT_ZQ, out + OUT_LOSS,
                                                 out + OUT_ENC, out + OUT_EMB);
}

// Round 7
// 259.332 us; speedup vs baseline: 103.3111x; 1.2137x over previous
//
#include <hip/hip_runtime.h>
#include <math.h>

#define N_TOTAL   32768
#define K_ENT     4096
#define DIM       64
#define BM        64
#define BK        128

typedef __attribute__((ext_vector_type(4))) float f32x4;
typedef __attribute__((ext_vector_type(8))) short bf16x8;
typedef __attribute__((ext_vector_type(4))) unsigned short u16x4;

// ws layout (float offsets) — total 1.065 MB (<= 1.2 MB demonstrated safe)
#define WS_CBN    0            // 4096 floats: 0.5*||w_k||^2
#define WS_WHI    4096         // 4096x64 ushort hi-plane (512 KB)
#define WS_WLO    135168       // 4096x64 ushort lo-plane (512 KB)
// out layout (fp32 element offsets)
#define OUT_ZQ    0
#define OUT_IDX   2097152
#define OUT_LOSS  2129920
#define OUT_ENC   2134016
#define OUT_EMB   2138112

#define NEG_BIG   -3.0e38f

__device__ __forceinline__ float bf2f(unsigned short u) {
  return __uint_as_float(((unsigned int)u) << 16);
}
__device__ __forceinline__ unsigned short f2bf(float f) {  // RNE
  unsigned int b = __float_as_uint(f);
  return (unsigned short)((b + 0x7fffu + ((b >> 16) & 1u)) >> 16);
}
__device__ __forceinline__ bool better(float a, int ia, float b, int ib) {
  return (a > b) || (a == b && ia < ib);
}

__global__ __launch_bounds__(256) void cbnorm_half_kernel(
    const float* __restrict__ w, float* __restrict__ cbn) {
  int k = blockIdx.x * 256 + threadIdx.x;
  const float4* p = (const float4*)(w + (size_t)k * DIM);
  float s = 0.f;
  #pragma unroll
  for (int i = 0; i < 16; ++i) {
    float4 v = p[i];
    s = fmaf(v.x, v.x, s); s = fmaf(v.y, v.y, s);
    s = fmaf(v.z, v.z, s); s = fmaf(v.w, v.w, s);
  }
  cbn[k] = 0.5f * s;
}

// split w into exact bf16 hi/lo planes (hi = RNE(w); lo = RNE(w - hi))
__global__ __launch_bounds__(256) void wsplit_kernel(
    const float* __restrict__ w, unsigned short* __restrict__ whi,
    unsigned short* __restrict__ wlo) {
  int i = blockIdx.x * 256 + threadIdx.x;      // 0..65535, float4 units
  float4 v = ((const float4*)w)[i];
  float f[4] = {v.x, v.y, v.z, v.w};
  u16x4 h, l;
  #pragma unroll
  for (int j = 0; j < 4; ++j) {
    unsigned short hb = f2bf(f[j]);
    h[j] = hb;
    l[j] = f2bf(f[j] - bf2f(hb));
  }
  ((u16x4*)whi)[i] = h;
  ((u16x4*)wlo)[i] = l;
}

// MFMA argmax: block = 64 rows x all K; 4 waves, each 32 rows x 64 entries of
// a BK=128 chunk. A (z) split to bf16 hi/lo in registers from global (no LDS).
// B (w) staged from pre-split planes into XOR-swizzled LDS (slot ^= e&7) so
// 16-lane b128 column reads sit at the bank-bandwidth floor. Dots via 3-term
// split MFMA (hi*hi + hi*lo + lo*hi), err ~1e-4; running top-2 per row in
// registers; LDS tail merge + exact fp64 rescore of the two finalists.
__global__ __launch_bounds__(256, 2) void argmax_kernel(
    const float* __restrict__ z, const float* __restrict__ w,
    const unsigned short* __restrict__ whi,
    const unsigned short* __restrict__ wlo,
    const float* __restrict__ cbn, float* __restrict__ out_idx) {
  __shared__ unsigned short wS[2][BK][DIM];  // 32 KB  [plane][entry][k]
  __shared__ float cvS[BM * 64];             // 16 KB  tail scores
  __shared__ float cjS[BM * 64];             // 16 KB  tail indices (as float)

  const int tid = threadIdx.x;
  const int n0  = blockIdx.x * BM;
  const int wv  = tid >> 6;        // wave 0..3
  const int ln  = tid & 63;
  const int g   = ln >> 4;         // k-group 0..3
  const int lm  = ln & 15;
  const int rb  = (wv & 1) * 32;   // wave row base
  const int eb  = (wv >> 1) * 64;  // wave entry base within chunk

  // ---- A fragments: rows rb+rt*16+lm, k = s*32+g*8..+7 (pi-consistent) ----
  bf16x8 ah[2][2], al[2][2];
  #pragma unroll
  for (int rt = 0; rt < 2; ++rt) {
    const float* zr = z + (size_t)(n0 + rb + rt * 16 + lm) * DIM;
    #pragma unroll
    for (int s = 0; s < 2; ++s) {
      float4 f0 = *(const float4*)(zr + s * 32 + g * 8);
      float4 f1 = *(const float4*)(zr + s * 32 + g * 8 + 4);
      float ff[8] = {f0.x, f0.y, f0.z, f0.w, f1.x, f1.y, f1.z, f1.w};
      bf16x8 h, lo;
      #pragma unroll
      for (int i = 0; i < 8; ++i) {
        unsigned short hb = f2bf(ff[i]);
        h[i]  = (short)hb;
        lo[i] = (short)f2bf(ff[i] - bf2f(hb));
      }
      ah[rt][s] = h;
      al[rt][s] = lo;
    }
  }

  float tv1[8], tv2[8];
  int   ti1[8], ti2[8];
  #pragma unroll
  for (int i = 0; i < 8; ++i) {
    tv1[i] = NEG_BIG; tv2[i] = NEG_BIG; ti1[i] = 0; ti2[i] = 0;
  }

  for (int kc = 0; kc < K_ENT; kc += BK) {
    __syncthreads();                 // prev chunk's wS reads done
    // stage both planes, swizzled 16B slots: LDS[e][sl] = glob[e][sl^(e&7)]
    #pragma unroll
    for (int it = 0; it < 4; ++it) {
      int u = it * 256 + tid;        // 16B-unit 0..1023
      int e = u >> 3, gg = u & 7;
      bf16x8 hv = *(const bf16x8*)(whi + (size_t)(kc + e) * DIM + gg * 8);
      bf16x8 lv = *(const bf16x8*)(wlo + (size_t)(kc + e) * DIM + gg * 8);
      int sl = gg ^ (e & 7);
      *(bf16x8*)&wS[0][e][sl * 8] = hv;
      *(bf16x8*)&wS[1][e][sl * 8] = lv;
    }
    __syncthreads();                 // wS ready

    f32x4 acc[2][4];
    #pragma unroll
    for (int rt = 0; rt < 2; ++rt)
      #pragma unroll
      for (int ct = 0; ct < 4; ++ct)
        acc[rt][ct] = (f32x4){0.f, 0.f, 0.f, 0.f};

    #pragma unroll
    for (int ct = 0; ct < 4; ++ct) {
      const int e = eb + ct * 16 + lm;
      #pragma unroll
      for (int s = 0; s < 2; ++s) {
        const int sl = (s * 4 + g) ^ (e & 7);
        bf16x8 bh = *(const bf16x8*)&wS[0][e][sl * 8];
        bf16x8 bl = *(const bf16x8*)&wS[1][e][sl * 8];
        #pragma unroll
        for (int rt = 0; rt < 2; ++rt) {
          acc[rt][ct] = __builtin_amdgcn_mfma_f32_16x16x32_bf16(
              ah[rt][s], bh, acc[rt][ct], 0, 0, 0);
          acc[rt][ct] = __builtin_amdgcn_mfma_f32_16x16x32_bf16(
              al[rt][s], bh, acc[rt][ct], 0, 0, 0);
          acc[rt][ct] = __builtin_amdgcn_mfma_f32_16x16x32_bf16(
              ah[rt][s], bl, acc[rt][ct], 0, 0, 0);
        }
      }
    }

    // running top-2: score = dot - 0.5*||w||^2 (monotone in sim)
    #pragma unroll
    for (int ct = 0; ct < 4; ++ct) {
      const int eg2 = kc + eb + ct * 16 + lm;
      const float cb = cbn[eg2];
      #pragma unroll
      for (int rt = 0; rt < 2; ++rt)
        #pragma unroll
        for (int j = 0; j < 4; ++j) {
          const int so = rt * 4 + j;
          float sc = acc[rt][ct][j] - cb;
          if (better(sc, eg2, tv1[so], ti1[so])) {
            tv2[so] = tv1[so]; ti2[so] = ti1[so];
            tv1[so] = sc;      ti1[so] = eg2;
          } else if (better(sc, eg2, tv2[so], ti2[so])) {
            tv2[so] = sc; ti2[so] = eg2;
          }
        }
    }
  }

  // ---- tail: dump per-thread top-2 to dedicated LDS, serial merge ----
  #pragma unroll
  for (int rt = 0; rt < 2; ++rt)
    #pragma unroll
    for (int j = 0; j < 4; ++j) {
      const int r  = rb + rt * 16 + g * 4 + j;   // D row = (l>>4)*4+reg (m89)
      const int sl = (wv >> 1) * 16 + lm;
      const int so = rt * 4 + j;
      cvS[r * 64 + sl]      = tv1[so];
      cjS[r * 64 + sl]      = (float)ti1[so];
      cvS[r * 64 + 32 + sl] = tv2[so];
      cjS[r * 64 + 32 + sl] = (float)ti2[so];
    }
  __syncthreads();

  if (tid < BM) {
    const int r = tid;
    float b1 = NEG_BIG, b2 = NEG_BIG;
    int   j1 = 0, j2 = 0;
    for (int s = 0; s < 64; ++s) {
      float v = cvS[r * 64 + s];
      int   jj = (int)cjS[r * 64 + s];
      if (better(v, jj, b1, j1)) { b2 = b1; j2 = j1; b1 = v; j1 = jj; }
      else if (better(v, jj, b2, j2)) { b2 = v; j2 = jj; }
    }
    // exact fp64 rescore of the two finalists: sd = 2*dot(z,w) - ||w||^2
    const float* zr = z + (size_t)(n0 + r) * DIM;
    double best = -1.0e300;
    int win = (j1 >= 0 && j1 < K_ENT) ? j1 : 0;
    for (int t = 0; t < 2; ++t) {
      int c = t ? j2 : j1;
      if (c < 0 || c >= K_ENT) continue;
      double td = 0.0, ud = 0.0;
      for (int d = 0; d < DIM; ++d) {
        double zv = (double)zr[d];
        double wv2 = (double)w[(size_t)c * DIM + d];
        td = fma(zv, wv2, td);
        ud = fma(wv2, wv2, ud);
      }
      double sd = 2.0 * td - ud;
      if (sd > best || (sd == best && c < win)) { best = sd; win = c; }
    }
    out_idx[n0 + r] = (float)win;
  }
}

// one block per (b,s): 8 heads x 64 dims = 512 threads
__global__ __launch_bounds__(512) void gather_kernel(
    const float* __restrict__ z, const float* __restrict__ w,
    const float* __restrict__ idxf, float* __restrict__ out_zq,
    float* __restrict__ out_loss, float* __restrict__ enc,
    float* __restrict__ emb) {
  int bs = blockIdx.x;
  int tid = threadIdx.x;
  int h = tid >> 6, d = tid & 63;
  int n = bs * 8 + h;
  int k = (int)idxf[n];
  k = (k < 0) ? 0 : ((k > K_ENT - 1) ? (K_ENT - 1) : k);
  float zv = z[(size_t)n * DIM + d];
  float wv = w[(size_t)k * DIM + d];
  float st = zv + (wv - zv);
  out_zq[(size_t)n * DIM + d] = st;
  float diff = zv - wv;
  float s = diff * diff;
  #pragma unroll
  for (int m = 32; m >= 1; m >>= 1) s += __shfl_down(s, m, 64);
  __shared__ float red[8];
  if ((tid & 63) == 0) red[tid >> 6] = s;
  __syncthreads();
  if (tid == 0) {
    float t = 0.f;
    #pragma unroll
    for (int i = 0; i < 8; ++i) t += red[i];
    out_loss[bs] = t * (1.0f / 512.0f);
  }
  atomicAdd(&emb[(size_t)k * DIM + d], zv);
  if (d == 0) atomicAdd(&enc[k], 1.0f);
}

extern "C" void kernel_launch(void* const* d_in, const int* in_sizes, int n_in,
                              void* d_out, int out_size, void* d_ws, size_t ws_size,
                              hipStream_t stream) {
  const float* z = (const float*)d_in[0];
  const float* w = (const float*)d_in[1];
  float* ws  = (float*)d_ws;
  float* cbn = ws + WS_CBN;
  unsigned short* whi = (unsigned short*)(ws + WS_WHI);
  unsigned short* wlo = (unsigned short*)(ws + WS_WLO);
  float* out = (float*)d_out;

  hipMemsetAsync(out + OUT_ENC, 0, (size_t)(4096 + 262144) * sizeof(float),
                 stream);

  cbnorm_half_kernel<<<K_ENT / 256, 256, 0, stream>>>(w, cbn);
  wsplit_kernel<<<(K_ENT * DIM / 4) / 256, 256, 0, stream>>>(w, whi, wlo);
  argmax_kernel<<<N_TOTAL / BM, 256, 0, stream>>>(z, w, whi, wlo, cbn,
                                                  out + OUT_IDX);
  gather_kernel<<<N_TOTAL / 8, 512, 0, stream>>>(z, w, out + OUT_IDX,
                                                 out + OUT_ZQ, out + OUT_LOSS,
                                                 out + OUT_ENC, out + OUT_EMB);
}

// Round 8
// 127.611 us; speedup vs baseline: 209.9494x; 2.0322x over previous
//
#include <hip/hip_runtime.h>
#include <math.h>

#define N_TOTAL   32768
#define K_ENT     4096
#define DIM       64
#define BM        64
#define BK        128
#define CAP       32
#define EPS       1.0f

typedef __attribute__((ext_vector_type(4))) float f32x4;
typedef __attribute__((ext_vector_type(8))) short bf16x8;
typedef __attribute__((ext_vector_type(4))) unsigned short u16x4;

// ws layout (float offsets) — total 528 KB
#define WS_NCB    0            // 4096 floats: -0.5*||w_k||^2
#define WS_WHI    4096         // 4096x64 ushort hi-plane (512 KB)
// out layout (fp32 element offsets)
#define OUT_ZQ    0
#define OUT_IDX   2097152
#define OUT_LOSS  2129920
#define OUT_ENC   2134016
#define OUT_EMB   2138112

#define NEG_BIG   -3.0e38f

__device__ __forceinline__ float bf2f(unsigned short u) {
  return __uint_as_float(((unsigned int)u) << 16);
}
__device__ __forceinline__ unsigned short f2bf(float f) {  // RNE
  unsigned int b = __float_as_uint(f);
  return (unsigned short)((b + 0x7fffu + ((b >> 16) & 1u)) >> 16);
}

__global__ __launch_bounds__(256) void negcbnorm_kernel(
    const float* __restrict__ w, float* __restrict__ ncb) {
  int k = blockIdx.x * 256 + threadIdx.x;
  const float4* p = (const float4*)(w + (size_t)k * DIM);
  float s = 0.f;
  #pragma unroll
  for (int i = 0; i < 16; ++i) {
    float4 v = p[i];
    s = fmaf(v.x, v.x, s); s = fmaf(v.y, v.y, s);
    s = fmaf(v.z, v.z, s); s = fmaf(v.w, v.w, s);
  }
  ncb[k] = -0.5f * s;
}

__global__ __launch_bounds__(256) void wsplit_kernel(
    const float* __restrict__ w, unsigned short* __restrict__ whi) {
  int i = blockIdx.x * 256 + threadIdx.x;      // 0..65535, float4 units
  float4 v = ((const float4*)w)[i];
  u16x4 h;
  h[0] = f2bf(v.x); h[1] = f2bf(v.y); h[2] = f2bf(v.z); h[3] = f2bf(v.w);
  ((u16x4*)whi)[i] = h;
}

// Two-sweep MFMA argmax. Block = 64 rows x all K; 4 waves each own 32 rows x
// 64 entries of a BK=128 chunk. A (z->bf16 hi) lives in registers (both
// sweeps); B (w hi-plane) staged into XOR-swizzled LDS (slot ^= e&7).
// C-init = -0.5||w||^2 so acc IS the score. Pass 1 keeps a per-row running
// max (v_max3 chain, no index tracking). Pass 2 recomputes identical scores
// and pushes entries >= rowmax-EPS into a per-row candidate list (shared
// atomics; set is deterministic). Tail: exact fp64 rescore of candidates,
// lowest-index tie-break (np argmax semantics).
__global__ __launch_bounds__(256, 2) void argmax_kernel(
    const float* __restrict__ z, const float* __restrict__ w,
    const unsigned short* __restrict__ whi,
    const float* __restrict__ ncb, float* __restrict__ out_idx) {
  __shared__ unsigned short wS[BK][DIM];   // 16 KB, swizzled 16B slots
  __shared__ float pmax[BM][33];           // 8.25 KB (padded stride)
  __shared__ float rowThr[BM];
  __shared__ int   cnt[BM];
  __shared__ int   cand[BM][CAP];          // 8 KB

  const int tid = threadIdx.x;
  const int n0  = blockIdx.x * BM;
  const int wv  = tid >> 6;        // wave 0..3
  const int ln  = tid & 63;
  const int g   = ln >> 4;         // k-group 0..3
  const int lm  = ln & 15;
  const int rb  = (wv & 1) * 32;   // wave row base
  const int eb  = (wv >> 1) * 64;  // wave entry base within chunk

  // ---- A fragments (hi plane): rows rb+rt*16+lm, k = s*32+g*8..+7 ----
  bf16x8 ah[2][2];
  #pragma unroll
  for (int rt = 0; rt < 2; ++rt) {
    const float* zr = z + (size_t)(n0 + rb + rt * 16 + lm) * DIM;
    #pragma unroll
    for (int s = 0; s < 2; ++s) {
      float4 f0 = *(const float4*)(zr + s * 32 + g * 8);
      float4 f1 = *(const float4*)(zr + s * 32 + g * 8 + 4);
      float ff[8] = {f0.x, f0.y, f0.z, f0.w, f1.x, f1.y, f1.z, f1.w};
      bf16x8 h;
      #pragma unroll
      for (int i = 0; i < 8; ++i) h[i] = (short)f2bf(ff[i]);
      ah[rt][s] = h;
    }
  }

  float m[8];
  #pragma unroll
  for (int i = 0; i < 8; ++i) m[i] = NEG_BIG;

  // ================= PASS 1: per-row max =================
  for (int kc = 0; kc < K_ENT; kc += BK) {
    __syncthreads();
    #pragma unroll
    for (int it = 0; it < 4; ++it) {
      int u = it * 256 + tid;      // 16B-unit 0..1023
      int e = u >> 3, gg = u & 7;
      bf16x8 hv = *(const bf16x8*)(whi + (size_t)(kc + e) * DIM + gg * 8);
      *(bf16x8*)&wS[e][(gg ^ (e & 7)) * 8] = hv;
    }
    __syncthreads();

    float nc[4];
    #pragma unroll
    for (int ct = 0; ct < 4; ++ct) nc[ct] = ncb[kc + eb + ct * 16 + lm];

    f32x4 acc[2][4];
    #pragma unroll
    for (int rt = 0; rt < 2; ++rt)
      #pragma unroll
      for (int ct = 0; ct < 4; ++ct)
        acc[rt][ct] = (f32x4){nc[ct], nc[ct], nc[ct], nc[ct]};

    #pragma unroll
    for (int ct = 0; ct < 4; ++ct) {
      const int e = eb + ct * 16 + lm;
      #pragma unroll
      for (int s = 0; s < 2; ++s) {
        const int sl = (s * 4 + g) ^ (e & 7);
        bf16x8 bh = *(const bf16x8*)&wS[e][sl * 8];
        #pragma unroll
        for (int rt = 0; rt < 2; ++rt)
          acc[rt][ct] = __builtin_amdgcn_mfma_f32_16x16x32_bf16(
              ah[rt][s], bh, acc[rt][ct], 0, 0, 0);
      }
    }

    #pragma unroll
    for (int rt = 0; rt < 2; ++rt)
      #pragma unroll
      for (int j = 0; j < 4; ++j) {
        const int so = rt * 4 + j;
        float t = fmaxf(fmaxf(acc[rt][0][j], acc[rt][1][j]), acc[rt][2][j]);
        m[so] = fmaxf(fmaxf(t, acc[rt][3][j]), m[so]);
      }
  }

  // per-thread maxes -> pmax grid -> per-row threshold
  const int cw = (wv >> 1) * 16 + lm;
  #pragma unroll
  for (int rt = 0; rt < 2; ++rt)
    #pragma unroll
    for (int j = 0; j < 4; ++j)
      pmax[rb + rt * 16 + g * 4 + j][cw] = m[rt * 4 + j];
  __syncthreads();
  if (tid < BM) {
    float mm = NEG_BIG;
    for (int s = 0; s < 32; ++s) mm = fmaxf(mm, pmax[tid][s]);
    rowThr[tid] = mm - EPS;
    cnt[tid] = 0;
  }
  __syncthreads();

  float thr[8];
  #pragma unroll
  for (int rt = 0; rt < 2; ++rt)
    #pragma unroll
    for (int j = 0; j < 4; ++j)
      thr[rt * 4 + j] = rowThr[rb + rt * 16 + g * 4 + j];

  // ================= PASS 2: match & collect =================
  for (int kc = 0; kc < K_ENT; kc += BK) {
    __syncthreads();
    #pragma unroll
    for (int it = 0; it < 4; ++it) {
      int u = it * 256 + tid;
      int e = u >> 3, gg = u & 7;
      bf16x8 hv = *(const bf16x8*)(whi + (size_t)(kc + e) * DIM + gg * 8);
      *(bf16x8*)&wS[e][(gg ^ (e & 7)) * 8] = hv;
    }
    __syncthreads();

    float nc[4];
    #pragma unroll
    for (int ct = 0; ct < 4; ++ct) nc[ct] = ncb[kc + eb + ct * 16 + lm];

    f32x4 acc[2][4];
    #pragma unroll
    for (int rt = 0; rt < 2; ++rt)
      #pragma unroll
      for (int ct = 0; ct < 4; ++ct)
        acc[rt][ct] = (f32x4){nc[ct], nc[ct], nc[ct], nc[ct]};

    #pragma unroll
    for (int ct = 0; ct < 4; ++ct) {
      const int e = eb + ct * 16 + lm;
      #pragma unroll
      for (int s = 0; s < 2; ++s) {
        const int sl = (s * 4 + g) ^ (e & 7);
        bf16x8 bh = *(const bf16x8*)&wS[e][sl * 8];
        #pragma unroll
        for (int rt = 0; rt < 2; ++rt)
          acc[rt][ct] = __builtin_amdgcn_mfma_f32_16x16x32_bf16(
              ah[rt][s], bh, acc[rt][ct], 0, 0, 0);
      }
    }

    #pragma unroll
    for (int ct = 0; ct < 4; ++ct) {
      const int eg2 = kc + eb + ct * 16 + lm;
      #pragma unroll
      for (int rt = 0; rt < 2; ++rt)
        #pragma unroll
        for (int j = 0; j < 4; ++j) {
          float s = acc[rt][ct][j];
          if (__builtin_expect(s >= thr[rt * 4 + j], 0)) {
            int r = rb + rt * 16 + g * 4 + j;
            int p = atomicAdd(&cnt[r], 1);
            if (p < CAP) cand[r][p] = eg2;
          }
        }
    }
  }
  __syncthreads();

  // ---- tail: exact fp64 rescore of candidates ----
  if (tid < BM) {
    const int r = tid;
    int nn = cnt[r];
    nn = (nn > CAP) ? CAP : nn;
    const float* zr = z + (size_t)(n0 + r) * DIM;
    double best = -1.0e300;
    int win = 0;
    for (int p = 0; p < nn; ++p) {
      int c = cand[r][p];
      double td = 0.0, ud = 0.0;
      for (int d = 0; d < DIM; ++d) {
        double zv = (double)zr[d];
        double wv2 = (double)w[(size_t)c * DIM + d];
        td = fma(zv, wv2, td);
        ud = fma(wv2, wv2, ud);
      }
      double sd = 2.0 * td - ud;
      if (sd > best || (sd == best && c < win)) { best = sd; win = c; }
    }
    out_idx[n0 + r] = (float)win;
  }
}

// one block per (b,s): 8 heads x 64 dims = 512 threads
__global__ __launch_bounds__(512) void gather_kernel(
    const float* __restrict__ z, const float* __restrict__ w,
    const float* __restrict__ idxf, float* __restrict__ out_zq,
    float* __restrict__ out_loss, float* __restrict__ enc,
    float* __restrict__ emb) {
  int bs = blockIdx.x;
  int tid = threadIdx.x;
  int h = tid >> 6, d = tid & 63;
  int n = bs * 8 + h;
  int k = (int)idxf[n];
  k = (k < 0) ? 0 : ((k > K_ENT - 1) ? (K_ENT - 1) : k);
  float zv = z[(size_t)n * DIM + d];
  float wv = w[(size_t)k * DIM + d];
  float st = zv + (wv - zv);
  out_zq[(size_t)n * DIM + d] = st;
  float diff = zv - wv;
  float s = diff * diff;
  #pragma unroll
  for (int mm = 32; mm >= 1; mm >>= 1) s += __shfl_down(s, mm, 64);
  __shared__ float red[8];
  if ((tid & 63) == 0) red[tid >> 6] = s;
  __syncthreads();
  if (tid == 0) {
    float t = 0.f;
    #pragma unroll
    for (int i = 0; i < 8; ++i) t += red[i];
    out_loss[bs] = t * (1.0f / 512.0f);
  }
  atomicAdd(&emb[(size_t)k * DIM + d], zv);
  if (d == 0) atomicAdd(&enc[k], 1.0f);
}

extern "C" void kernel_launch(void* const* d_in, const int* in_sizes, int n_in,
                              void* d_out, int out_size, void* d_ws, size_t ws_size,
                              hipStream_t stream) {
  const float* z = (const float*)d_in[0];
  const float* w = (const float*)d_in[1];
  float* ws  = (float*)d_ws;
  float* ncb = ws + WS_NCB;
  unsigned short* whi = (unsigned short*)(ws + WS_WHI);
  float* out = (float*)d_out;

  hipMemsetAsync(out + OUT_ENC, 0, (size_t)(4096 + 262144) * sizeof(float),
                 stream);

  negcbnorm_kernel<<<K_ENT / 256, 256, 0, stream>>>(w, ncb);
  wsplit_kernel<<<(K_ENT * DIM / 4) / 256, 256, 0, stream>>>(w, whi);
  argmax_kernel<<<N_TOTAL / BM, 256, 0, stream>>>(z, w, whi, ncb,
                                                  out + OUT_IDX);
  gather_kernel<<<N_TOTAL / 8, 512, 0, stream>>>(z, w, out + OUT_IDX,
                                                 out + OUT_ZQ, out + OUT_LOSS,
                                                 out + OUT_ENC, out + OUT_EMB);
}

// Round 9
// 120.411 us; speedup vs baseline: 222.5031x; 1.0598x over previous
//
#include <hip/hip_runtime.h>
#include <math.h>

#define N_TOTAL   32768
#define K_ENT     4096
#define DIM       64
#define BM        64
#define BK        128
#define CAP       32
#define EPS       1.0f

typedef __attribute__((ext_vector_type(4))) float f32x4;
typedef __attribute__((ext_vector_type(8))) short bf16x8;
typedef __attribute__((ext_vector_type(4))) unsigned short u16x4;

// ws layout (float offsets) — total 528 KB
#define WS_NCB    0            // 4096 floats: -0.5*||w_k||^2
#define WS_WHI    4096         // 4096x64 ushort hi-plane (512 KB)
// out layout (fp32 element offsets)
#define OUT_ZQ    0
#define OUT_IDX   2097152
#define OUT_LOSS  2129920
#define OUT_ENC   2134016
#define OUT_EMB   2138112

#define NEG_BIG   -3.0e38f

__device__ __forceinline__ float bf2f(unsigned short u) {
  return __uint_as_float(((unsigned int)u) << 16);
}
__device__ __forceinline__ unsigned short f2bf(float f) {  // RNE
  unsigned int b = __float_as_uint(f);
  return (unsigned short)((b + 0x7fffu + ((b >> 16) & 1u)) >> 16);
}

__global__ __launch_bounds__(256) void negcbnorm_kernel(
    const float* __restrict__ w, float* __restrict__ ncb) {
  int k = blockIdx.x * 256 + threadIdx.x;
  const float4* p = (const float4*)(w + (size_t)k * DIM);
  float s = 0.f;
  #pragma unroll
  for (int i = 0; i < 16; ++i) {
    float4 v = p[i];
    s = fmaf(v.x, v.x, s); s = fmaf(v.y, v.y, s);
    s = fmaf(v.z, v.z, s); s = fmaf(v.w, v.w, s);
  }
  ncb[k] = -0.5f * s;
}

__global__ __launch_bounds__(256) void wsplit_kernel(
    const float* __restrict__ w, unsigned short* __restrict__ whi) {
  int i = blockIdx.x * 256 + threadIdx.x;      // 0..65535, float4 units
  float4 v = ((const float4*)w)[i];
  u16x4 h;
  h[0] = f2bf(v.x); h[1] = f2bf(v.y); h[2] = f2bf(v.z); h[3] = f2bf(v.w);
  ((u16x4*)whi)[i] = h;
}

// Two-sweep MFMA argmax, double-buffered LDS + register prefetch:
// one barrier per chunk; next chunk's w-tile and ncb values are issued into
// registers at the top of the iteration so their L2 latency hides under the
// current chunk's MFMAs. Pass 1: per-row max only. Pass 2: recompute
// identical scores, collect entries >= rowmax-EPS (deterministic set).
// Tail: exact fp64 rescore of candidates, lowest-index tie-break.
__global__ __launch_bounds__(256, 2) void argmax_kernel(
    const float* __restrict__ z, const float* __restrict__ w,
    const unsigned short* __restrict__ whi,
    const float* __restrict__ ncb, float* __restrict__ out_idx) {
  __shared__ unsigned short wS[2][BK][DIM];  // 32 KB, swizzled 16B slots
  __shared__ float pmax[BM][33];             // 8.25 KB (padded stride)
  __shared__ float rowThr[BM];
  __shared__ int   cnt[BM];
  __shared__ int   cand[BM][CAP];            // 8 KB

  const int tid = threadIdx.x;
  const int n0  = blockIdx.x * BM;
  const int wv  = tid >> 6;        // wave 0..3
  const int ln  = tid & 63;
  const int g   = ln >> 4;         // k-group 0..3
  const int lm  = ln & 15;
  const int rb  = (wv & 1) * 32;   // wave row base
  const int eb  = (wv >> 1) * 64;  // wave entry base within chunk

  // staging geometry (per thread, 4 x 16B units)
  const int se0 = tid >> 3;                   // entry for unit 0 (+32/unit)
  const int sg  = tid & 7;                    // 16B-slot within entry

  // ---- A fragments (hi plane): rows rb+rt*16+lm, k = s*32+g*8..+7 ----
  bf16x8 ah[2][2];
  #pragma unroll
  for (int rt = 0; rt < 2; ++rt) {
    const float* zr = z + (size_t)(n0 + rb + rt * 16 + lm) * DIM;
    #pragma unroll
    for (int s = 0; s < 2; ++s) {
      float4 f0 = *(const float4*)(zr + s * 32 + g * 8);
      float4 f1 = *(const float4*)(zr + s * 32 + g * 8 + 4);
      float ff[8] = {f0.x, f0.y, f0.z, f0.w, f1.x, f1.y, f1.z, f1.w};
      bf16x8 h;
      #pragma unroll
      for (int i = 0; i < 8; ++i) h[i] = (short)f2bf(ff[i]);
      ah[rt][s] = h;
    }
  }

  float m[8];
  #pragma unroll
  for (int i = 0; i < 8; ++i) m[i] = NEG_BIG;

  bf16x8 wpre[4];
  float  ncc[4];   // nc for the chunk about to be computed
  float  ncp[4];   // nc prefetch

  // ================= PASS 1: per-row max =================
  // prologue: chunk 0 -> regs -> wS[0]
  #pragma unroll
  for (int it = 0; it < 4; ++it)
    wpre[it] = *(const bf16x8*)(whi + (size_t)(se0 + it * 32) * DIM + sg * 8);
  #pragma unroll
  for (int ct = 0; ct < 4; ++ct) ncc[ct] = ncb[eb + ct * 16 + lm];
  #pragma unroll
  for (int it = 0; it < 4; ++it) {
    int e = se0 + it * 32;
    *(bf16x8*)&wS[0][e][(sg ^ (e & 7)) * 8] = wpre[it];
  }
  __syncthreads();

  for (int kc = 0; kc < K_ENT; kc += BK) {
    const int cur = (kc >> 7) & 1;
    const bool more = (kc + BK) < K_ENT;
    if (more) {                      // issue next chunk loads (hidden by MFMA)
      #pragma unroll
      for (int it = 0; it < 4; ++it)
        wpre[it] = *(const bf16x8*)(whi +
                     (size_t)(kc + BK + se0 + it * 32) * DIM + sg * 8);
      #pragma unroll
      for (int ct = 0; ct < 4; ++ct)
        ncp[ct] = ncb[kc + BK + eb + ct * 16 + lm];
    }

    f32x4 acc[2][4];
    #pragma unroll
    for (int rt = 0; rt < 2; ++rt)
      #pragma unroll
      for (int ct = 0; ct < 4; ++ct)
        acc[rt][ct] = (f32x4){ncc[ct], ncc[ct], ncc[ct], ncc[ct]};

    #pragma unroll
    for (int ct = 0; ct < 4; ++ct) {
      const int e = eb + ct * 16 + lm;
      #pragma unroll
      for (int s = 0; s < 2; ++s) {
        const int sl = (s * 4 + g) ^ (e & 7);
        bf16x8 bh = *(const bf16x8*)&wS[cur][e][sl * 8];
        #pragma unroll
        for (int rt = 0; rt < 2; ++rt)
          acc[rt][ct] = __builtin_amdgcn_mfma_f32_16x16x32_bf16(
              ah[rt][s], bh, acc[rt][ct], 0, 0, 0);
      }
    }

    #pragma unroll
    for (int rt = 0; rt < 2; ++rt)
      #pragma unroll
      for (int j = 0; j < 4; ++j) {
        const int so = rt * 4 + j;
        float t = fmaxf(fmaxf(acc[rt][0][j], acc[rt][1][j]), acc[rt][2][j]);
        m[so] = fmaxf(fmaxf(t, acc[rt][3][j]), m[so]);
      }

    if (more) {                      // write next buffer, carry nc
      #pragma unroll
      for (int it = 0; it < 4; ++it) {
        int e = se0 + it * 32;
        *(bf16x8*)&wS[cur ^ 1][e][(sg ^ (e & 7)) * 8] = wpre[it];
      }
      #pragma unroll
      for (int ct = 0; ct < 4; ++ct) ncc[ct] = ncp[ct];
    }
    __syncthreads();                 // single barrier per chunk (dbuf)
  }

  // per-thread maxes -> pmax grid -> per-row threshold
  const int cw = (wv >> 1) * 16 + lm;
  #pragma unroll
  for (int rt = 0; rt < 2; ++rt)
    #pragma unroll
    for (int j = 0; j < 4; ++j)
      pmax[rb + rt * 16 + g * 4 + j][cw] = m[rt * 4 + j];
  __syncthreads();
  if (tid < BM) {
    float mm = NEG_BIG;
    for (int s = 0; s < 32; ++s) mm = fmaxf(mm, pmax[tid][s]);
    rowThr[tid] = mm - EPS;
    cnt[tid] = 0;
  }
  __syncthreads();

  float thr[8];
  #pragma unroll
  for (int rt = 0; rt < 2; ++rt)
    #pragma unroll
    for (int j = 0; j < 4; ++j)
      thr[rt * 4 + j] = rowThr[rb + rt * 16 + g * 4 + j];

  // ================= PASS 2: match & collect =================
  #pragma unroll
  for (int it = 0; it < 4; ++it)
    wpre[it] = *(const bf16x8*)(whi + (size_t)(se0 + it * 32) * DIM + sg * 8);
  #pragma unroll
  for (int ct = 0; ct < 4; ++ct) ncc[ct] = ncb[eb + ct * 16 + lm];
  #pragma unroll
  for (int it = 0; it < 4; ++it) {
    int e = se0 + it * 32;
    *(bf16x8*)&wS[0][e][(sg ^ (e & 7)) * 8] = wpre[it];
  }
  __syncthreads();

  for (int kc = 0; kc < K_ENT; kc += BK) {
    const int cur = (kc >> 7) & 1;
    const bool more = (kc + BK) < K_ENT;
    if (more) {
      #pragma unroll
      for (int it = 0; it < 4; ++it)
        wpre[it] = *(const bf16x8*)(whi +
                     (size_t)(kc + BK + se0 + it * 32) * DIM + sg * 8);
      #pragma unroll
      for (int ct = 0; ct < 4; ++ct)
        ncp[ct] = ncb[kc + BK + eb + ct * 16 + lm];
    }

    f32x4 acc[2][4];
    #pragma unroll
    for (int rt = 0; rt < 2; ++rt)
      #pragma unroll
      for (int ct = 0; ct < 4; ++ct)
        acc[rt][ct] = (f32x4){ncc[ct], ncc[ct], ncc[ct], ncc[ct]};

    #pragma unroll
    for (int ct = 0; ct < 4; ++ct) {
      const int e = eb + ct * 16 + lm;
      #pragma unroll
      for (int s = 0; s < 2; ++s) {
        const int sl = (s * 4 + g) ^ (e & 7);
        bf16x8 bh = *(const bf16x8*)&wS[cur][e][sl * 8];
        #pragma unroll
        for (int rt = 0; rt < 2; ++rt)
          acc[rt][ct] = __builtin_amdgcn_mfma_f32_16x16x32_bf16(
              ah[rt][s], bh, acc[rt][ct], 0, 0, 0);
      }
    }

    #pragma unroll
    for (int ct = 0; ct < 4; ++ct) {
      const int eg2 = kc + eb + ct * 16 + lm;
      #pragma unroll
      for (int rt = 0; rt < 2; ++rt)
        #pragma unroll
        for (int j = 0; j < 4; ++j) {
          float s = acc[rt][ct][j];
          if (__builtin_expect(s >= thr[rt * 4 + j], 0)) {
            int r = rb + rt * 16 + g * 4 + j;
            int p = atomicAdd(&cnt[r], 1);
            if (p < CAP) cand[r][p] = eg2;
          }
        }
    }

    if (more) {
      #pragma unroll
      for (int it = 0; it < 4; ++it) {
        int e = se0 + it * 32;
        *(bf16x8*)&wS[cur ^ 1][e][(sg ^ (e & 7)) * 8] = wpre[it];
      }
      #pragma unroll
      for (int ct = 0; ct < 4; ++ct) ncc[ct] = ncp[ct];
    }
    __syncthreads();
  }

  // ---- tail: exact fp64 rescore of candidates ----
  if (tid < BM) {
    const int r = tid;
    int nn = cnt[r];
    nn = (nn > CAP) ? CAP : nn;
    const float* zr = z + (size_t)(n0 + r) * DIM;
    double best = -1.0e300;
    int win = 0;
    for (int p = 0; p < nn; ++p) {
      int c = cand[r][p];
      double td = 0.0, ud = 0.0;
      for (int d = 0; d < DIM; ++d) {
        double zv = (double)zr[d];
        double wv2 = (double)w[(size_t)c * DIM + d];
        td = fma(zv, wv2, td);
        ud = fma(wv2, wv2, ud);
      }
      double sd = 2.0 * td - ud;
      if (sd > best || (sd == best && c < win)) { best = sd; win = c; }
    }
    out_idx[n0 + r] = (float)win;
  }
}

// one block per (b,s): 8 heads x 64 dims = 512 threads
__global__ __launch_bounds__(512) void gather_kernel(
    const float* __restrict__ z, const float* __restrict__ w,
    const float* __restrict__ idxf, float* __restrict__ out_zq,
    float* __restrict__ out_loss, float* __restrict__ enc,
    float* __restrict__ emb) {
  int bs = blockIdx.x;
  int tid = threadIdx.x;
  int h = tid >> 6, d = tid & 63;
  int n = bs * 8 + h;
  int k = (int)idxf[n];
  k = (k < 0) ? 0 : ((k > K_ENT - 1) ? (K_ENT - 1) : k);
  float zv = z[(size_t)n * DIM + d];
  float wv = w[(size_t)k * DIM + d];
  float st = zv + (wv - zv);
  out_zq[(size_t)n * DIM + d] = st;
  float diff = zv - wv;
  float s = diff * diff;
  #pragma unroll
  for (int mm = 32; mm >= 1; mm >>= 1) s += __shfl_down(s, mm, 64);
  __shared__ float red[8];
  if ((tid & 63) == 0) red[tid >> 6] = s;
  __syncthreads();
  if (tid == 0) {
    float t = 0.f;
    #pragma unroll
    for (int i = 0; i < 8; ++i) t += red[i];
    out_loss[bs] = t * (1.0f / 512.0f);
  }
  atomicAdd(&emb[(size_t)k * DIM + d], zv);
  if (d == 0) atomicAdd(&enc[k], 1.0f);
}

extern "C" void kernel_launch(void* const* d_in, const int* in_sizes, int n_in,
                              void* d_out, int out_size, void* d_ws, size_t ws_size,
                              hipStream_t stream) {
  const float* z = (const float*)d_in[0];
  const float* w = (const float*)d_in[1];
  float* ws  = (float*)d_ws;
  float* ncb = ws + WS_NCB;
  unsigned short* whi = (unsigned short*)(ws + WS_WHI);
  float* out = (float*)d_out;

  hipMemsetAsync(out + OUT_ENC, 0, (size_t)(4096 + 262144) * sizeof(float),
                 stream);

  negcbnorm_kernel<<<K_ENT / 256, 256, 0, stream>>>(w, ncb);
  wsplit_kernel<<<(K_ENT * DIM / 4) / 256, 256, 0, stream>>>(w, whi);
  argmax_kernel<<<N_TOTAL / BM, 256, 0, stream>>>(z, w, whi, ncb,
                                                  out + OUT_IDX);
  gather_kernel<<<N_TOTAL / 8, 512, 0, stream>>>(z, w, out + OUT_IDX,
                                                 out + OUT_ZQ, out + OUT_LOSS,
                                                 out + OUT_ENC, out + OUT_EMB);
}

// Round 10
// 113.457 us; speedup vs baseline: 236.1422x; 1.0613x over previous
//
#include <hip/hip_runtime.h>
#include <math.h>

#define N_TOTAL   32768
#define K_ENT     4096
#define DIM       64
#define BM        64
#define BK        128
#define CAP       32
#define EPS       1.0f

typedef __attribute__((ext_vector_type(4))) float f32x4;
typedef __attribute__((ext_vector_type(8))) short bf16x8;
typedef __attribute__((ext_vector_type(4))) unsigned short u16x4;

// ws layout (float offsets) — total 528 KB
#define WS_NCB    0            // 4096 floats: -0.5*||w_k||^2
#define WS_WHI    4096         // 4096x64 ushort hi-plane (512 KB)
// out layout (fp32 element offsets)
#define OUT_ZQ    0
#define OUT_IDX   2097152
#define OUT_LOSS  2129920
#define OUT_ENC   2134016
#define OUT_EMB   2138112

#define NEG_BIG   -3.0e38f

__device__ __forceinline__ float bf2f(unsigned short u) {
  return __uint_as_float(((unsigned int)u) << 16);
}
__device__ __forceinline__ unsigned short f2bf(float f) {  // RNE
  unsigned int b = __float_as_uint(f);
  return (unsigned short)((b + 0x7fffu + ((b >> 16) & 1u)) >> 16);
}

// fused: bf16 hi-plane split + ncb = -0.5*||w_k||^2 (16-lane shfl reduce)
__global__ __launch_bounds__(256) void prep_kernel(
    const float* __restrict__ w, unsigned short* __restrict__ whi,
    float* __restrict__ ncb) {
  int i = blockIdx.x * 256 + threadIdx.x;      // float4 unit, 0..65535
  float4 v = ((const float4*)w)[i];
  u16x4 h;
  h[0] = f2bf(v.x); h[1] = f2bf(v.y); h[2] = f2bf(v.z); h[3] = f2bf(v.w);
  ((u16x4*)whi)[i] = h;
  float s = fmaf(v.x, v.x, fmaf(v.y, v.y, fmaf(v.z, v.z, v.w * v.w)));
  s += __shfl_xor(s, 1); s += __shfl_xor(s, 2);
  s += __shfl_xor(s, 4); s += __shfl_xor(s, 8);
  if ((threadIdx.x & 15) == 0) ncb[i >> 4] = -0.5f * s;
}

// Two-sweep MFMA argmax, NO LDS in the main loop: each of 4 waves covers all
// 64 rows x a private 32-entry column stripe per BK=128 chunk; B fragments
// (entry=lane&15, k=(lane>>4)*8) load straight global->reg from the L2-
// resident hi-plane. 2-chunk software pipeline, statically named reg sets.
// Pass 1: per-row max (fmax chains only). Pass 2: identical scores (same
// MFMA sequence + C-init => bit-identical), collect entries >= rowmax-EPS.
// Tail: exact fp64 rescore of candidates, lowest-index tie-break.
__global__ __launch_bounds__(256, 2) void argmax_kernel(
    const float* __restrict__ z, const float* __restrict__ w,
    const unsigned short* __restrict__ whi,
    const float* __restrict__ ncb, float* __restrict__ out_idx) {
  __shared__ float pmax[BM][65];   // 16.6 KB, padded (conflict-free col scan)
  __shared__ float rowThr[BM];
  __shared__ int   cnt[BM];
  __shared__ int   cand[BM][CAP];  // 8 KB

  const int tid = threadIdx.x;
  const int n0  = blockIdx.x * BM;
  const int wv  = tid >> 6;        // wave 0..3
  const int ln  = tid & 63;
  const int g   = ln >> 4;         // k-group 0..3
  const int lm  = ln & 15;
  const int ecol = wv * 32 + lm;   // wave's entry column (+ct*16)

  // ---- A fragments (hi plane, registers): rows rt*16+lm, k=s*32+g*8 ----
  bf16x8 ah[4][2];
  #pragma unroll
  for (int rt = 0; rt < 4; ++rt) {
    const float* zr = z + (size_t)(n0 + rt * 16 + lm) * DIM;
    #pragma unroll
    for (int s = 0; s < 2; ++s) {
      float4 f0 = *(const float4*)(zr + s * 32 + g * 8);
      float4 f1 = *(const float4*)(zr + s * 32 + g * 8 + 4);
      float ff[8] = {f0.x, f0.y, f0.z, f0.w, f1.x, f1.y, f1.z, f1.w};
      bf16x8 h;
      #pragma unroll
      for (int i = 0; i < 8; ++i) h[i] = (short)f2bf(ff[i]);
      ah[rt][s] = h;
    }
  }

  bf16x8 bA[2][2], bB[2][2];
  float  ncA[2], ncB[2];

  auto loadB = [&](int kcb, bf16x8 (&bv)[2][2], float (&nc)[2]) {
    #pragma unroll
    for (int ct = 0; ct < 2; ++ct) {
      const int ent = kcb + ecol + ct * 16;
      nc[ct] = ncb[ent];
      const unsigned short* wr = whi + (size_t)ent * DIM + g * 8;
      bv[ct][0] = *(const bf16x8*)(wr);
      bv[ct][1] = *(const bf16x8*)(wr + 32);
    }
  };

  // ================= PASS 1: per-row max =================
  float m[16];
  #pragma unroll
  for (int i = 0; i < 16; ++i) m[i] = NEG_BIG;

  auto comp1 = [&](const bf16x8 (&bv)[2][2], const float (&nc)[2]) {
    f32x4 acc[4][2];
    #pragma unroll
    for (int rt = 0; rt < 4; ++rt)
      #pragma unroll
      for (int ct = 0; ct < 2; ++ct)
        acc[rt][ct] = (f32x4){nc[ct], nc[ct], nc[ct], nc[ct]};
    #pragma unroll
    for (int ct = 0; ct < 2; ++ct)
      #pragma unroll
      for (int s = 0; s < 2; ++s)
        #pragma unroll
        for (int rt = 0; rt < 4; ++rt)
          acc[rt][ct] = __builtin_amdgcn_mfma_f32_16x16x32_bf16(
              ah[rt][s], bv[ct][s], acc[rt][ct], 0, 0, 0);
    #pragma unroll
    for (int rt = 0; rt < 4; ++rt)
      #pragma unroll
      for (int j = 0; j < 4; ++j)
        m[rt * 4 + j] = fmaxf(fmaxf(acc[rt][0][j], acc[rt][1][j]),
                              m[rt * 4 + j]);
  };

  loadB(0, bA, ncA);
  for (int kc = 0; kc < K_ENT; kc += 2 * BK) {
    loadB(kc + BK, bB, ncB);
    comp1(bA, ncA);
    if (kc + 2 * BK < K_ENT) loadB(kc + 2 * BK, bA, ncA);
    comp1(bB, ncB);
  }

  // per-thread maxes -> pmax grid -> per-row threshold
  #pragma unroll
  for (int rt = 0; rt < 4; ++rt)
    #pragma unroll
    for (int j = 0; j < 4; ++j)
      pmax[rt * 16 + g * 4 + j][wv * 16 + lm] = m[rt * 4 + j];
  __syncthreads();
  if (tid < BM) {
    float mm = NEG_BIG;
    for (int s = 0; s < 64; ++s) mm = fmaxf(mm, pmax[tid][s]);
    rowThr[tid] = mm - EPS;
    cnt[tid] = 0;
  }
  __syncthreads();

  float thr[16];
  #pragma unroll
  for (int rt = 0; rt < 4; ++rt)
    #pragma unroll
    for (int j = 0; j < 4; ++j)
      thr[rt * 4 + j] = rowThr[rt * 16 + g * 4 + j];

  // ================= PASS 2: match & collect =================
  auto comp2 = [&](int kcb, const bf16x8 (&bv)[2][2], const float (&nc)[2]) {
    f32x4 acc[4][2];
    #pragma unroll
    for (int rt = 0; rt < 4; ++rt)
      #pragma unroll
      for (int ct = 0; ct < 2; ++ct)
        acc[rt][ct] = (f32x4){nc[ct], nc[ct], nc[ct], nc[ct]};
    #pragma unroll
    for (int ct = 0; ct < 2; ++ct)
      #pragma unroll
      for (int s = 0; s < 2; ++s)
        #pragma unroll
        for (int rt = 0; rt < 4; ++rt)
          acc[rt][ct] = __builtin_amdgcn_mfma_f32_16x16x32_bf16(
              ah[rt][s], bv[ct][s], acc[rt][ct], 0, 0, 0);
    #pragma unroll
    for (int ct = 0; ct < 2; ++ct) {
      const int eg2 = kcb + ecol + ct * 16;
      #pragma unroll
      for (int rt = 0; rt < 4; ++rt)
        #pragma unroll
        for (int j = 0; j < 4; ++j) {
          if (__builtin_expect(acc[rt][ct][j] >= thr[rt * 4 + j], 0)) {
            int r = rt * 16 + g * 4 + j;
            int p = atomicAdd(&cnt[r], 1);
            if (p < CAP) cand[r][p] = eg2;
          }
        }
    }
  };

  loadB(0, bA, ncA);
  for (int kc = 0; kc < K_ENT; kc += 2 * BK) {
    loadB(kc + BK, bB, ncB);
    comp2(kc, bA, ncA);
    if (kc + 2 * BK < K_ENT) loadB(kc + 2 * BK, bA, ncA);
    comp2(kc + BK, bB, ncB);
  }
  __syncthreads();

  // ---- tail: exact fp64 rescore of candidates ----
  if (tid < BM) {
    const int r = tid;
    int nn = cnt[r];
    nn = (nn > CAP) ? CAP : nn;
    const float* zr = z + (size_t)(n0 + r) * DIM;
    double best = -1.0e300;
    int win = 0;
    for (int p = 0; p < nn; ++p) {
      int c = cand[r][p];
      double td = 0.0, ud = 0.0;
      for (int d = 0; d < DIM; ++d) {
        double zv = (double)zr[d];
        double wv2 = (double)w[(size_t)c * DIM + d];
        td = fma(zv, wv2, td);
        ud = fma(wv2, wv2, ud);
      }
      double sd = 2.0 * td - ud;
      if (sd > best || (sd == best && c < win)) { best = sd; win = c; }
    }
    out_idx[n0 + r] = (float)win;
  }
}

// one block per (b,s): 8 heads x 64 dims = 512 threads
__global__ __launch_bounds__(512) void gather_kernel(
    const float* __restrict__ z, const float* __restrict__ w,
    const float* __restrict__ idxf, float* __restrict__ out_zq,
    float* __restrict__ out_loss, float* __restrict__ enc,
    float* __restrict__ emb) {
  int bs = blockIdx.x;
  int tid = threadIdx.x;
  int h = tid >> 6, d = tid & 63;
  int n = bs * 8 + h;
  int k = (int)idxf[n];
  k = (k < 0) ? 0 : ((k > K_ENT - 1) ? (K_ENT - 1) : k);
  float zv = z[(size_t)n * DIM + d];
  float wv = w[(size_t)k * DIM + d];
  float st = zv + (wv - zv);
  out_zq[(size_t)n * DIM + d] = st;
  float diff = zv - wv;
  float s = diff * diff;
  #pragma unroll
  for (int mm = 32; mm >= 1; mm >>= 1) s += __shfl_down(s, mm, 64);
  __shared__ float red[8];
  if ((tid & 63) == 0) red[tid >> 6] = s;
  __syncthreads();
  if (tid == 0) {
    float t = 0.f;
    #pragma unroll
    for (int i = 0; i < 8; ++i) t += red[i];
    out_loss[bs] = t * (1.0f / 512.0f);
  }
  atomicAdd(&emb[(size_t)k * DIM + d], zv);
  if (d == 0) atomicAdd(&enc[k], 1.0f);
}

extern "C" void kernel_launch(void* const* d_in, const int* in_sizes, int n_in,
                              void* d_out, int out_size, void* d_ws, size_t ws_size,
                              hipStream_t stream) {
  const float* z = (const float*)d_in[0];
  const float* w = (const float*)d_in[1];
  float* ws  = (float*)d_ws;
  float* ncb = ws + WS_NCB;
  unsigned short* whi = (unsigned short*)(ws + WS_WHI);
  float* out = (float*)d_out;

  hipMemsetAsync(out + OUT_ENC, 0, (size_t)(4096 + 262144) * sizeof(float),
                 stream);

  prep_kernel<<<(K_ENT * DIM / 4) / 256, 256, 0, stream>>>(w, whi, ncb);
  argmax_kernel<<<N_TOTAL / BM, 256, 0, stream>>>(z, w, whi, ncb,
                                                  out + OUT_IDX);
  gather_kernel<<<N_TOTAL / 8, 512, 0, stream>>>(z, w, out + OUT_IDX,
                                                 out + OUT_ZQ, out + OUT_LOSS,
                                                 out + OUT_ENC, out + OUT_EMB);
}